// Round 4
// baseline (1315.610 us; speedup 1.0000x reference)
//
#include <hip/hip_runtime.h>
#include <stdint.h>

// Problem constants (reference: B,S,D,H = 2,2048,2048,16; DH=128)
constexpr int kBz = 2;
constexpr int kSz = 2048;
constexpr int kDz = 2048;
constexpr int kHz = 16;
constexpr int kDH = 128;
constexpr int kMz = kBz * kSz;  // 4096 rows of x

typedef __attribute__((ext_vector_type(8)))  short bf16x8;
typedef __attribute__((ext_vector_type(16))) float f32x16;

__device__ __forceinline__ ushort f2bf_rne(float f) {
    const uint u = __float_as_uint(f);
    return (ushort)((u + 0x7FFFu + ((u >> 16) & 1u)) >> 16);
}
__device__ __forceinline__ float bf2f(ushort h) {
    return __uint_as_float(((uint)h) << 16);
}
// split fp32 -> (hi = truncated bf16, lo = rne bf16 of residual); packed pairs
__device__ __forceinline__ void cvt_split(const float4 v, uint2& hi, uint2& lo) {
    const ushort h0 = (ushort)(__float_as_uint(v.x) >> 16);
    const ushort h1 = (ushort)(__float_as_uint(v.y) >> 16);
    const ushort h2 = (ushort)(__float_as_uint(v.z) >> 16);
    const ushort h3 = (ushort)(__float_as_uint(v.w) >> 16);
    const ushort l0 = f2bf_rne(v.x - bf2f(h0));
    const ushort l1 = f2bf_rne(v.y - bf2f(h1));
    const ushort l2 = f2bf_rne(v.z - bf2f(h2));
    const ushort l3 = f2bf_rne(v.w - bf2f(h3));
    hi.x = (uint)h0 | ((uint)h1 << 16);
    hi.y = (uint)h2 | ((uint)h3 << 16);
    lo.x = (uint)l0 | ((uint)l1 << 16);
    lo.y = (uint)l2 | ((uint)l3 << 16);
}

// ---------------------------------------------------------------------------
// Kernel A: fused QKV projection via split-bf16 MFMA (error-compensated).
// C ≈ xhi*whi + xhi*wlo + xlo*whi (lo*lo dropped, ~2^-17 relative error).
// BM=BN=128, BK=32, 4 waves (2x2), per-wave 64x64 = 2x2 frags of
// v_mfma_f32_32x32x16_bf16.  Q,K outputs stored as SPLIT bf16 hi/lo planes
// (consumed by MFMA QK^T downstream); V stored fp32.  All in (B,H,S,DH).
// ---------------------------------------------------------------------------
__global__ __launch_bounds__(256)
void qkv_proj_kernel(const float* __restrict__ x,
                     const float* __restrict__ Wq, const float* __restrict__ Wk,
                     const float* __restrict__ Wv,
                     const float* __restrict__ bq, const float* __restrict__ bk,
                     const float* __restrict__ bv,
                     ushort* __restrict__ Qhi, ushort* __restrict__ Qlo,
                     ushort* __restrict__ Khi, ushort* __restrict__ Klo,
                     float* __restrict__ Vo)
{
    const int z = blockIdx.z;
    const float* W    = (z == 0) ? Wq : (z == 1) ? Wk : Wv;
    const float* bias = (z == 0) ? bq : (z == 1) ? bk : bv;

    // plane stride 1032 ushorts = 2064 B = 129*16 B (16B-aligned)
    __shared__ ushort AsHi[4 * 1032];
    __shared__ ushort AsLo[4 * 1032];
    __shared__ ushort BsHi[4 * 1032];
    __shared__ ushort BsLo[4 * 1032];

    const int tid  = threadIdx.x;
    const int lane = tid & 63;
    const int wid  = tid >> 6;
    const int wr   = (wid >> 1) * 64;   // wave row offset in tile
    const int wc   = (wid & 1) * 64;    // wave col offset in tile
    const int row0 = blockIdx.y * 128;
    const int col0 = blockIdx.x * 128;

    f32x16 acc[2][2];
#pragma unroll
    for (int fi = 0; fi < 2; ++fi)
#pragma unroll
        for (int fj = 0; fj < 2; ++fj)
#pragma unroll
            for (int e = 0; e < 16; ++e) acc[fi][fj][e] = 0.0f;

    for (int kt = 0; kt < kDz; kt += 32) {
#pragma unroll
        for (int t = 0; t < 4; ++t) {
            const int idx = tid + t * 256;   // 0..1023
            const int m   = idx >> 3;        // row 0..127
            const int q   = idx & 7;         // float4 index along k
            const int off = (q >> 1) * 1032 + m * 8 + (q & 1) * 4;  // ushort idx
            {
                const float4 av = *(const float4*)&x[(size_t)(row0 + m) * kDz + kt + q * 4];
                uint2 ph, pl;
                cvt_split(av, ph, pl);
                *(uint2*)&AsHi[off] = ph;
                *(uint2*)&AsLo[off] = pl;
            }
            {
                const float4 wv4 = *(const float4*)&W[(size_t)(col0 + m) * kDz + kt + q * 4];
                uint2 ph, pl;
                cvt_split(wv4, ph, pl);
                *(uint2*)&BsHi[off] = ph;
                *(uint2*)&BsLo[off] = pl;
            }
        }
        __syncthreads();

#pragma unroll
        for (int ks = 0; ks < 2; ++ks) {
            const int base = (ks * 2 + (lane >> 5)) * 1032;
            bf16x8 ah[2], al[2], bh[2], bl[2];
#pragma unroll
            for (int f = 0; f < 2; ++f) {
                const int ma = (wr + f * 32 + (lane & 31)) * 8;
                ah[f] = *(const bf16x8*)&AsHi[base + ma];
                al[f] = *(const bf16x8*)&AsLo[base + ma];
                const int nb = (wc + f * 32 + (lane & 31)) * 8;
                bh[f] = *(const bf16x8*)&BsHi[base + nb];
                bl[f] = *(const bf16x8*)&BsLo[base + nb];
            }
#pragma unroll
            for (int fi = 0; fi < 2; ++fi)
#pragma unroll
                for (int fj = 0; fj < 2; ++fj) {
                    acc[fi][fj] = __builtin_amdgcn_mfma_f32_32x32x16_bf16(
                        ah[fi], bh[fj], acc[fi][fj], 0, 0, 0);
                    acc[fi][fj] = __builtin_amdgcn_mfma_f32_32x32x16_bf16(
                        ah[fi], bl[fj], acc[fi][fj], 0, 0, 0);
                    acc[fi][fj] = __builtin_amdgcn_mfma_f32_32x32x16_bf16(
                        al[fi], bh[fj], acc[fi][fj], 0, 0, 0);
                }
        }
        __syncthreads();
    }

    // ---- epilogue: bias + store; Q/K as split-bf16 planes, V as fp32 ----
    const int head = blockIdx.x;
    ushort* HiP = (z == 0) ? Qhi : Khi;
    ushort* LoP = (z == 0) ? Qlo : Klo;
#pragma unroll
    for (int fj = 0; fj < 2; ++fj) {
        const int dh  = wc + fj * 32 + (lane & 31);
        const float bvs = bias[head * kDH + dh];
#pragma unroll
        for (int fi = 0; fi < 2; ++fi) {
            const int rb = row0 + wr + fi * 32 + ((lane >> 5) << 2);
#pragma unroll
            for (int g = 0; g < 4; ++g)
#pragma unroll
                for (int e = 0; e < 4; ++e) {
                    const int row = rb + g * 8 + e;
                    const int bb  = row >> 11;
                    const int ss  = row & (kSz - 1);
                    const size_t idx =
                        ((size_t)(bb * kHz + head) * kSz + ss) * kDH + dh;
                    const float val = acc[fi][fj][g * 4 + e] + bvs;
                    if (z == 2) {
                        Vo[idx] = val;
                    } else {
                        const ushort hb = (ushort)(__float_as_uint(val) >> 16);
                        const ushort lb = f2bf_rne(val - bf2f(hb));
                        HiP[idx] = hb;
                        LoP[idx] = lb;
                    }
                }
        }
    }
}

// ---------------------------------------------------------------------------
// Kernel B: flash attention, QK^T via swapped-operand split-bf16 MFMA,
// PV in fp32 VALU (round-2 structure), fused per-head output projection.
//
// Block: 256 thr = 4 waves, QB=64, KVB=64.  wave (iw=wid&1, jw=wid>>1):
// iw picks the 32-query group, jw the 32-key group.  QK^T computes
// D = K_tile * Q^T per 32x32: D col = lane&31 = query i (HW-verified),
// D rows (regs) = key j -> softmax is in-register + one shfl_xor(32) +
// tiny LDS cross-wave merge.  P is written exp'd-unnormalized to Ps[j][i],
// then the round-2 VALU PV loop + fused out-projection run unchanged.
//
// LDS tiles (K hi/lo, Q staging) are 256B rows; fragment reads use the
// 16B-slot XOR swizzle c^=(row&15) -> every wave b128 access lands exactly
// 8 words/bank (even = conflict-free).
// ---------------------------------------------------------------------------
__global__ __launch_bounds__(256)
void attn_fused_kernel(const ushort* __restrict__ Qhi, const ushort* __restrict__ Qlo,
                       const ushort* __restrict__ Khi, const ushort* __restrict__ Klo,
                       const float* __restrict__ Vg,
                       const uint8_t* __restrict__ mask,
                       const float* __restrict__ Wo, const float* __restrict__ bo,
                       float* __restrict__ out)
{
    __shared__ __align__(16) ushort KLs[2][64 * 128];  // 32 KB; also Q stage; also O-park (f32)
    __shared__ float U[64 * 128];    // V tile / Wo halves (32 KB)
    __shared__ float Ps[64 * 68];    // 17 KB
    __shared__ float mbiasS[64];
    __shared__ float rmaxP[2][64];
    __shared__ float rsumP[2][64];
    __shared__ float alphaS[64];
    __shared__ float linvS[64];

    const int tid  = threadIdx.x;
    const int lane = tid & 63;
    const int wid  = tid >> 6;
    const int iw   = wid & 1;        // query 32-group
    const int jw   = wid >> 1;       // key 32-group
    const int half = lane >> 5;
    const int l31  = lane & 31;
    const int tx   = tid & 15;       // PV-phase mapping (round-2)
    const int ty   = tid >> 4;
    const int bh   = blockIdx.y;
    const int bb   = bh >> 4;
    const int h    = bh & 15;
    const int s0   = blockIdx.x * 64;

    const size_t plane = (size_t)bh * kSz * kDH;
    const ushort* QhiP = Qhi + plane;
    const ushort* QloP = Qlo + plane;
    const ushort* KhiP = Khi + plane;
    const ushort* KloP = Klo + plane;
    const float*  Vp   = Vg + plane;
    const float scale = 0.08838834764831845f;  // 1/sqrt(128)

    // mask byte-stride detection: uint8 bools vs int32-normalized (uniform)
    const uint32_t w0 = *(const uint32_t*)mask;
    const int mstride = ((w0 & 0xFFu) != 0u && ((w0 >> 8) & 0xFFu) != 0u) ? 1 : 4;
    const uint8_t* mp = mask + (size_t)bb * kSz * mstride;

    // ---- stage Q rows s0..s0+63 (hi/lo) swizzled, then frags to regs ----
#pragma unroll
    for (int t = 0; t < 4; ++t) {
        const int idx = tid + t * 256;     // 0..1023 = 64 rows x 16 chunks
        const int r   = idx >> 4;
        const int c   = idx & 15;
        const int dst = r * 128 + (c ^ (r & 15)) * 8;
        *(uint4*)&KLs[0][dst] = *(const uint4*)&QhiP[(size_t)(s0 + r) * kDH + c * 8];
        *(uint4*)&KLs[1][dst] = *(const uint4*)&QloP[(size_t)(s0 + r) * kDH + c * 8];
    }
    __syncthreads();

    bf16x8 qh[8], ql[8];
    {
        const int qrow = iw * 32 + l31;
#pragma unroll
        for (int ks = 0; ks < 8; ++ks) {
            const int cs = (ks * 2 + half) ^ (qrow & 15);
            qh[ks] = *(const bf16x8*)&KLs[0][qrow * 128 + cs * 8];
            ql[ks] = *(const bf16x8*)&KLs[1][qrow * 128 + cs * 8];
        }
    }
    __syncthreads();   // KLs free for K tiles

    float mx   = -1e38f;
    float lsum = 0.0f;
    float oacc[4][8];
#pragma unroll
    for (int r = 0; r < 4; ++r)
#pragma unroll
        for (int c = 0; c < 8; ++c) oacc[r][c] = 0.0f;

    for (int kt = 0; kt < kSz / 64; ++kt) {
        // ---- t0: stage K hi/lo (swizzled), V (linear), mask bias ----
#pragma unroll
        for (int t = 0; t < 4; ++t) {
            const int idx = tid + t * 256;
            const int r   = idx >> 4;
            const int c   = idx & 15;
            const int dst = r * 128 + (c ^ (r & 15)) * 8;
            *(uint4*)&KLs[0][dst] = *(const uint4*)&KhiP[(size_t)(kt * 64 + r) * kDH + c * 8];
            *(uint4*)&KLs[1][dst] = *(const uint4*)&KloP[(size_t)(kt * 64 + r) * kDH + c * 8];
        }
#pragma unroll
        for (int t = 0; t < 8; ++t) {
            const int idx = tid + t * 256;
            const int j   = idx >> 5;
            const int dq  = idx & 31;
            *(float4*)&U[j * 128 + dq * 4] =
                *(const float4*)&Vp[(size_t)(kt * 64 + j) * kDH + dq * 4];
        }
        if (tid < 64)
            mbiasS[tid] = (mp[(size_t)(kt * 64 + tid) * mstride] != 0) ? 0.0f : -1e30f;
        __syncthreads();  // sync1

        // ---- t1: QK^T (swapped): D[j][i] for this wave's (jw, iw) ----
        f32x16 sf;
#pragma unroll
        for (int r = 0; r < 16; ++r) sf[r] = 0.0f;
        const int jrow = jw * 32 + l31;
#pragma unroll
        for (int ks = 0; ks < 8; ++ks) {
            const int cs = (ks * 2 + half) ^ (jrow & 15);
            const bf16x8 kh = *(const bf16x8*)&KLs[0][jrow * 128 + cs * 8];
            const bf16x8 kl = *(const bf16x8*)&KLs[1][jrow * 128 + cs * 8];
            sf = __builtin_amdgcn_mfma_f32_32x32x16_bf16(kh, qh[ks], sf, 0, 0, 0);
            sf = __builtin_amdgcn_mfma_f32_32x32x16_bf16(kh, ql[ks], sf, 0, 0, 0);
            sf = __builtin_amdgcn_mfma_f32_32x32x16_bf16(kl, qh[ks], sf, 0, 0, 0);
        }

        // ---- scale + mask + in-register row stats ----
        float sv[16];
        float rmax = -1e38f;
#pragma unroll
        for (int r = 0; r < 16; ++r) {
            const int jsub = (r & 3) + 8 * (r >> 2) + 4 * half;
            const float v  = sf[r] * scale + mbiasS[jw * 32 + jsub];
            sv[r] = v;
            rmax  = fmaxf(rmax, v);
        }
        rmax = fmaxf(rmax, __shfl_xor(rmax, 32));
        if (lane < 32) rmaxP[jw][iw * 32 + l31] = rmax;
        __syncthreads();  // sync2

        const int irow   = iw * 32 + l31;
        const float mnew = fmaxf(mx, fmaxf(rmaxP[0][irow], rmaxP[1][irow]));
        const float alpha = __expf(mx - mnew);
        float rs = 0.0f;
#pragma unroll
        for (int r = 0; r < 16; ++r) {
            const float pv = __expf(sv[r] - mnew);
            sv[r] = pv;
            rs += pv;
        }
        rs += __shfl_xor(rs, 32);
        if (lane < 32) rsumP[jw][irow] = rs;
        if (jw == 0 && lane < 32) alphaS[irow] = alpha;
#pragma unroll
        for (int r = 0; r < 16; ++r) {
            const int jsub = (r & 3) + 8 * (r >> 2) + 4 * half;
            Ps[(jw * 32 + jsub) * 68 + irow] = sv[r];
        }
        mx = mnew;
        __syncthreads();  // sync3
        lsum = lsum * alpha + (rsumP[0][irow] + rsumP[1][irow]);

        // ---- t2: rescale + PV (round-2 VALU loop) ----
#pragma unroll
        for (int r = 0; r < 4; ++r) {
            const float a = alphaS[ty * 4 + r];
#pragma unroll
            for (int c = 0; c < 8; ++c) oacc[r][c] *= a;
        }
#pragma unroll 2
        for (int j = 0; j < 64; ++j) {
            const float4 p4 = *(const float4*)&Ps[j * 68 + ty * 4];
            const float4 va = *(const float4*)&U[j * 128 + tx * 4];
            const float4 vb = *(const float4*)&U[j * 128 + 64 + tx * 4];
            const float pa[4] = {p4.x, p4.y, p4.z, p4.w};
#pragma unroll
            for (int r = 0; r < 4; ++r) {
                oacc[r][0] += pa[r] * va.x;
                oacc[r][1] += pa[r] * va.y;
                oacc[r][2] += pa[r] * va.z;
                oacc[r][3] += pa[r] * va.w;
                oacc[r][4] += pa[r] * vb.x;
                oacc[r][5] += pa[r] * vb.y;
                oacc[r][6] += pa[r] * vb.z;
                oacc[r][7] += pa[r] * vb.w;
            }
        }
        __syncthreads();  // sync4
    }

    // ---- publish 1/l, then park normalized O (transposed+swizzled) ----
    if (jw == 0 && lane < 32) linvS[iw * 32 + l31] = 1.0f / lsum;
    __syncthreads();

    float* Opark = (float*)&KLs[0][0];   // 32 KB region reused
#pragma unroll
    for (int r = 0; r < 4; ++r) {
        const float inv = linvS[ty * 4 + r];
#pragma unroll
        for (int c = 0; c < 8; ++c) {
            const int d = (c < 4) ? (tx * 4 + c) : (64 + tx * 4 + (c - 4));
            Opark[d * 64 + ((ty * 4 + r) ^ (((d >> 2) & 15) << 2))] = oacc[r][c] * inv;
        }
    }

    // ---- fused per-head output projection (round-2 verbatim) ----
#pragma unroll 1
    for (int hf = 0; hf < 2; ++hf) {
        __syncthreads();
#pragma unroll
        for (int t = 0; t < 8; ++t) {
            const int idx = tid + t * 256;
            const int e   = idx >> 5;
            const int dq  = idx & 31;
            const float4 w =
                *(const float4*)&Wo[(size_t)(h * 128 + hf * 64 + e) * kDH + dq * 4];
            const int szw = (dq & 15) << 2;
            U[(dq * 4 + 0) * 64 + (e ^ szw)] = w.x;
            U[(dq * 4 + 1) * 64 + (e ^ szw)] = w.y;
            U[(dq * 4 + 2) * 64 + (e ^ szw)] = w.z;
            U[(dq * 4 + 3) * 64 + (e ^ szw)] = w.w;
        }
        __syncthreads();

        float yacc[4][4];
#pragma unroll
        for (int r = 0; r < 4; ++r)
#pragma unroll
            for (int c = 0; c < 4; ++c) yacc[r][c] = 0.0f;

#pragma unroll 4
        for (int d = 0; d < 128; ++d) {
            const int szw = ((d >> 2) & 15) << 2;
            const float4 o4 = *(const float4*)&Opark[d * 64 + ((ty * 4) ^ szw)];
            const float4 w4 = *(const float4*)&U[d * 64 + ((tx * 4) ^ szw)];
            const float oa[4] = {o4.x, o4.y, o4.z, o4.w};
            const float wa[4] = {w4.x, w4.y, w4.z, w4.w};
#pragma unroll
            for (int r = 0; r < 4; ++r)
#pragma unroll
                for (int c = 0; c < 4; ++c) yacc[r][c] += oa[r] * wa[c];
        }

        const float4 bo4 = *(const float4*)&bo[h * 128 + hf * 64 + tx * 4];
#pragma unroll
        for (int r = 0; r < 4; ++r) {
            const int srow = s0 + ty * 4 + r;
            float4 y;
            y.x = yacc[r][0] + bo4.x;
            y.y = yacc[r][1] + bo4.y;
            y.z = yacc[r][2] + bo4.z;
            y.w = yacc[r][3] + bo4.w;
            *(float4*)&out[(size_t)(bb * kSz + srow) * kDz + h * kDH + hf * 64 + tx * 4] = y;
        }
    }
}

// ---------------------------------------------------------------------------
extern "C" void kernel_launch(void* const* d_in, const int* in_sizes, int n_in,
                              void* d_out, int out_size, void* d_ws, size_t ws_size,
                              hipStream_t stream)
{
    (void)in_sizes; (void)n_in; (void)out_size; (void)ws_size;
    const float*   x    = (const float*)d_in[0];
    const uint8_t* mask = (const uint8_t*)d_in[1];  // bool: 1B or int32 (detected)
    const float*   Wq   = (const float*)d_in[2];
    const float*   bq   = (const float*)d_in[3];
    const float*   Wk   = (const float*)d_in[4];
    const float*   bk   = (const float*)d_in[5];
    const float*   Wv   = (const float*)d_in[6];
    const float*   bv   = (const float*)d_in[7];
    const float*   Wo   = (const float*)d_in[8];
    const float*   bo   = (const float*)d_in[9];
    float* out = (float*)d_out;

    // workspace: Qhi,Qlo,Khi,Klo bf16 planes + V fp32, all (B,H,S,DH).
    // 4 x 16.78 MB + 33.55 MB = 100.66 MB (same footprint as 3 fp32 planes).
    const size_t plane = (size_t)kBz * kHz * kSz * kDH;  // 8,388,608 elems
    ushort* Qhi = (ushort*)d_ws;
    ushort* Qlo = Qhi + plane;
    ushort* Khi = Qlo + plane;
    ushort* Klo = Khi + plane;
    float*  Vb  = (float*)(Klo + plane);

    qkv_proj_kernel<<<dim3(kDz / 128, kMz / 128, 3), 256, 0, stream>>>(
        x, Wq, Wk, Wv, bq, bk, bv, Qhi, Qlo, Khi, Klo, Vb);
    attn_fused_kernel<<<dim3(kSz / 64, kBz * kHz), 256, 0, stream>>>(
        Qhi, Qlo, Khi, Klo, Vb, mask, Wo, bo, out);
}

// Round 5
// 950.524 us; speedup vs baseline: 1.3841x; 1.3841x over previous
//
#include <hip/hip_runtime.h>
#include <stdint.h>

// Problem constants (reference: B,S,D,H = 2,2048,2048,16; DH=128)
constexpr int kBz = 2;
constexpr int kSz = 2048;
constexpr int kDz = 2048;
constexpr int kHz = 16;
constexpr int kDH = 128;
constexpr int kMz = kBz * kSz;  // 4096 rows of x

typedef __attribute__((ext_vector_type(8)))  short bf16x8;
typedef __attribute__((ext_vector_type(16))) float f32x16;

__device__ __forceinline__ ushort f2bf_rne(float f) {
    const uint u = __float_as_uint(f);
    return (ushort)((u + 0x7FFFu + ((u >> 16) & 1u)) >> 16);
}
__device__ __forceinline__ ushort f2bf_hi(float f) {
    return (ushort)(__float_as_uint(f) >> 16);
}
__device__ __forceinline__ float bf2f(ushort h) {
    return __uint_as_float(((uint)h) << 16);
}
// split fp32 -> (hi = truncated bf16, lo = rne bf16 of residual); packed pairs
__device__ __forceinline__ void cvt_split(const float4 v, uint2& hi, uint2& lo) {
    const ushort h0 = f2bf_hi(v.x);
    const ushort h1 = f2bf_hi(v.y);
    const ushort h2 = f2bf_hi(v.z);
    const ushort h3 = f2bf_hi(v.w);
    const ushort l0 = f2bf_rne(v.x - bf2f(h0));
    const ushort l1 = f2bf_rne(v.y - bf2f(h1));
    const ushort l2 = f2bf_rne(v.z - bf2f(h2));
    const ushort l3 = f2bf_rne(v.w - bf2f(h3));
    hi.x = (uint)h0 | ((uint)h1 << 16);
    hi.y = (uint)h2 | ((uint)h3 << 16);
    lo.x = (uint)l0 | ((uint)l1 << 16);
    lo.y = (uint)l2 | ((uint)l3 << 16);
}
// load 8 bf16 from an 8B-aligned (not necessarily 16B) address as 2x b64
__device__ __forceinline__ bf16x8 ld_b64x2(const ushort* p) {
    const ushort4 a = *(const ushort4*)p;
    const ushort4 b = *(const ushort4*)(p + 4);
    bf16x8 r;
    r[0] = (short)a.x; r[1] = (short)a.y; r[2] = (short)a.z; r[3] = (short)a.w;
    r[4] = (short)b.x; r[5] = (short)b.y; r[6] = (short)b.z; r[7] = (short)b.w;
    return r;
}

// ---------------------------------------------------------------------------
// Kernel W: split Wo (fp32, H x DH x DH) into bf16 hi/lo planes.
// ---------------------------------------------------------------------------
__global__ __launch_bounds__(256)
void wo_split_kernel(const float* __restrict__ Wo,
                     ushort* __restrict__ Wohi, ushort* __restrict__ Wolo)
{
    const int i = (blockIdx.x * 256 + threadIdx.x) * 4;
    const float4 v = *(const float4*)&Wo[i];
    uint2 ph, pl;
    cvt_split(v, ph, pl);
    *(uint2*)&Wohi[i] = ph;
    *(uint2*)&Wolo[i] = pl;
}

// ---------------------------------------------------------------------------
// Kernel A: fused QKV projection via split-bf16 MFMA (validated round 4).
// Q,K stored as split bf16 hi/lo planes in (B,H,S,DH); V stored split AND
// TRANSPOSED: Vt[(b,h),d,s] hi/lo (feeds PV MFMA A-operand directly).
// ---------------------------------------------------------------------------
__global__ __launch_bounds__(256)
void qkv_proj_kernel(const float* __restrict__ x,
                     const float* __restrict__ Wq, const float* __restrict__ Wk,
                     const float* __restrict__ Wv,
                     const float* __restrict__ bq, const float* __restrict__ bk,
                     const float* __restrict__ bv,
                     ushort* __restrict__ Qhi, ushort* __restrict__ Qlo,
                     ushort* __restrict__ Khi, ushort* __restrict__ Klo,
                     ushort* __restrict__ Vthi, ushort* __restrict__ Vtlo)
{
    const int z = blockIdx.z;
    const float* W    = (z == 0) ? Wq : (z == 1) ? Wk : Wv;
    const float* bias = (z == 0) ? bq : (z == 1) ? bk : bv;

    // plane stride 1032 ushorts = 2064 B = 129*16 B (16B-aligned)
    __shared__ ushort AsHi[4 * 1032];
    __shared__ ushort AsLo[4 * 1032];
    __shared__ ushort BsHi[4 * 1032];
    __shared__ ushort BsLo[4 * 1032];

    const int tid  = threadIdx.x;
    const int lane = tid & 63;
    const int wid  = tid >> 6;
    const int wr   = (wid >> 1) * 64;   // wave row offset in tile
    const int wc   = (wid & 1) * 64;    // wave col offset in tile
    const int row0 = blockIdx.y * 128;
    const int col0 = blockIdx.x * 128;

    f32x16 acc[2][2];
#pragma unroll
    for (int fi = 0; fi < 2; ++fi)
#pragma unroll
        for (int fj = 0; fj < 2; ++fj)
#pragma unroll
            for (int e = 0; e < 16; ++e) acc[fi][fj][e] = 0.0f;

    for (int kt = 0; kt < kDz; kt += 32) {
#pragma unroll
        for (int t = 0; t < 4; ++t) {
            const int idx = tid + t * 256;   // 0..1023
            const int m   = idx >> 3;        // row 0..127
            const int q   = idx & 7;         // float4 index along k
            const int off = (q >> 1) * 1032 + m * 8 + (q & 1) * 4;  // ushort idx
            {
                const float4 av = *(const float4*)&x[(size_t)(row0 + m) * kDz + kt + q * 4];
                uint2 ph, pl;
                cvt_split(av, ph, pl);
                *(uint2*)&AsHi[off] = ph;
                *(uint2*)&AsLo[off] = pl;
            }
            {
                const float4 wv4 = *(const float4*)&W[(size_t)(col0 + m) * kDz + kt + q * 4];
                uint2 ph, pl;
                cvt_split(wv4, ph, pl);
                *(uint2*)&BsHi[off] = ph;
                *(uint2*)&BsLo[off] = pl;
            }
        }
        __syncthreads();

#pragma unroll
        for (int ks = 0; ks < 2; ++ks) {
            const int base = (ks * 2 + (lane >> 5)) * 1032;
            bf16x8 ah[2], al[2], bh[2], bl[2];
#pragma unroll
            for (int f = 0; f < 2; ++f) {
                const int ma = (wr + f * 32 + (lane & 31)) * 8;
                ah[f] = *(const bf16x8*)&AsHi[base + ma];
                al[f] = *(const bf16x8*)&AsLo[base + ma];
                const int nb = (wc + f * 32 + (lane & 31)) * 8;
                bh[f] = *(const bf16x8*)&BsHi[base + nb];
                bl[f] = *(const bf16x8*)&BsLo[base + nb];
            }
#pragma unroll
            for (int fi = 0; fi < 2; ++fi)
#pragma unroll
                for (int fj = 0; fj < 2; ++fj) {
                    acc[fi][fj] = __builtin_amdgcn_mfma_f32_32x32x16_bf16(
                        ah[fi], bh[fj], acc[fi][fj], 0, 0, 0);
                    acc[fi][fj] = __builtin_amdgcn_mfma_f32_32x32x16_bf16(
                        ah[fi], bl[fj], acc[fi][fj], 0, 0, 0);
                    acc[fi][fj] = __builtin_amdgcn_mfma_f32_32x32x16_bf16(
                        al[fi], bh[fj], acc[fi][fj], 0, 0, 0);
                }
        }
        __syncthreads();
    }

    // ---- epilogue ----
    const int head = blockIdx.x;
    if (z < 2) {
        ushort* HiP = (z == 0) ? Qhi : Khi;
        ushort* LoP = (z == 0) ? Qlo : Klo;
#pragma unroll
        for (int fj = 0; fj < 2; ++fj) {
            const int dh  = wc + fj * 32 + (lane & 31);
            const float bvs = bias[head * kDH + dh];
#pragma unroll
            for (int fi = 0; fi < 2; ++fi) {
                const int rb = row0 + wr + fi * 32 + ((lane >> 5) << 2);
#pragma unroll
                for (int g = 0; g < 4; ++g)
#pragma unroll
                    for (int e = 0; e < 4; ++e) {
                        const int row = rb + g * 8 + e;
                        const int bb  = row >> 11;
                        const int ss  = row & (kSz - 1);
                        const size_t idx =
                            ((size_t)(bb * kHz + head) * kSz + ss) * kDH + dh;
                        const float val = acc[fi][fj][g * 4 + e] + bvs;
                        const ushort hb = f2bf_hi(val);
                        HiP[idx] = hb;
                        LoP[idx] = f2bf_rne(val - bf2f(hb));
                    }
            }
        }
    } else {
        // V: store transposed split planes Vt[(b,h),d,s]
#pragma unroll
        for (int fj = 0; fj < 2; ++fj) {
            const int dh  = wc + fj * 32 + (lane & 31);
            const float bvs = bias[head * kDH + dh];
#pragma unroll
            for (int fi = 0; fi < 2; ++fi) {
                const int rb = row0 + wr + fi * 32 + ((lane >> 5) << 2);
#pragma unroll
                for (int g = 0; g < 4; ++g) {
                    const int srow = rb + g * 8;     // 4 consecutive rows e=0..3
                    const int bb   = srow >> 11;
                    const int ss   = srow & (kSz - 1);
                    ushort4 h4, l4;
                    {
                        const float v0 = acc[fi][fj][g * 4 + 0] + bvs;
                        const float v1 = acc[fi][fj][g * 4 + 1] + bvs;
                        const float v2 = acc[fi][fj][g * 4 + 2] + bvs;
                        const float v3 = acc[fi][fj][g * 4 + 3] + bvs;
                        h4.x = f2bf_hi(v0); l4.x = f2bf_rne(v0 - bf2f(h4.x));
                        h4.y = f2bf_hi(v1); l4.y = f2bf_rne(v1 - bf2f(h4.y));
                        h4.z = f2bf_hi(v2); l4.z = f2bf_rne(v2 - bf2f(h4.z));
                        h4.w = f2bf_hi(v3); l4.w = f2bf_rne(v3 - bf2f(h4.w));
                    }
                    const size_t base =
                        ((size_t)((bb * kHz + head) * kDH + dh)) * kSz + ss;
                    *(ushort4*)&Vthi[base] = h4;
                    *(ushort4*)&Vtlo[base] = l4;
                }
            }
        }
    }
}

// ---------------------------------------------------------------------------
// Kernel B: all-MFMA flash attention + fused out-projection.
// 4 waves (iw=wid&1 -> 32-query group, jw=wid>>1 -> 32-key group), QB=KVB=64.
// QK^T: A=K-frags DIRECT FROM GLOBAL (L1/L2-resident), B=Q-frags in regs.
// Softmax: in-register + shfl_xor(32) + LDS cross-wave partials (validated).
// P^T staged split-bf16 in LDS Pt[i][j] (stride 68 shorts -> 2-way free).
// PV: O^T = Vt·P^T, A=Vt-frags direct from global, B=Pt from LDS.
// Epilogue: y^T = Wo·O^T via MFMA, A=Wo split planes global, B=O parked
// split in LDS (union over Pt).  3 barriers/tile; LDS ~35 KB -> 4 blocks/CU.
// ---------------------------------------------------------------------------
__global__ __launch_bounds__(256)
void attn_fused_kernel(const ushort* __restrict__ Qhi, const ushort* __restrict__ Qlo,
                       const ushort* __restrict__ Khi, const ushort* __restrict__ Klo,
                       const ushort* __restrict__ Vthi, const ushort* __restrict__ Vtlo,
                       const uint8_t* __restrict__ mask,
                       const ushort* __restrict__ Wohi, const ushort* __restrict__ Wolo,
                       const float* __restrict__ bo, float* __restrict__ out)
{
    // union buffer: Pt (2 planes 64x68 shorts, offs 0 / 4352)
    //               Os (2 planes 64x132 shorts, offs 0 / 8448)  = 33792 B
    __shared__ __align__(16) ushort UN[16896];
    __shared__ float rmaxP[2][64];
    __shared__ float rsumP[2][64];
    __shared__ float alphaS[64];
    __shared__ float linvS[64];
    ushort* PtHi = UN;
    ushort* PtLo = UN + 4352;
    ushort* OsHi = UN;
    ushort* OsLo = UN + 8448;

    const int tid  = threadIdx.x;
    const int lane = tid & 63;
    const int wid  = tid >> 6;
    const int half = lane >> 5;
    const int l31  = lane & 31;
    const int iw   = wid & 1;        // query 32-group (QK^T phase)
    const int jw   = wid >> 1;       // key 32-group   (QK^T phase)

    // XCD-aware swizzle: 1024 blocks = 8 XCDs x 128; each XCD gets 4
    // consecutive bh (keeps K/V planes L2-local).
    const int nb = (blockIdx.x & 7) * 128 + (blockIdx.x >> 3);
    const int bh = nb >> 5;
    const int qb = nb & 31;
    const int bb = bh >> 4;
    const int h  = bh & 15;
    const int s0 = qb * 64;

    const size_t plane = (size_t)bh * kSz * kDH;
    const ushort* QhiP = Qhi + plane;
    const ushort* QloP = Qlo + plane;
    const ushort* KhiP = Khi + plane;
    const ushort* KloP = Klo + plane;
    const ushort* VthP = Vthi + plane;
    const ushort* VtlP = Vtlo + plane;
    const float scale = 0.08838834764831845f;  // 1/sqrt(128)

    // mask byte-stride detection (validated): uint8 bools vs int32
    const uint32_t w0 = *(const uint32_t*)mask;
    const int mstride = ((w0 & 0xFFu) != 0u && ((w0 >> 8) & 0xFFu) != 0u) ? 1 : 4;
    const uint8_t* mp8 = mask + (size_t)bb * kSz;
    const int*    mp32 = (const int*)mask + (size_t)bb * kSz;

    // ---- Q fragments to registers (direct global) ----
    bf16x8 qh[8], ql[8];
    {
        const size_t qoff = (size_t)(s0 + iw * 32 + l31) * kDH;
#pragma unroll
        for (int ks = 0; ks < 8; ++ks) {
            const int c = 2 * ks + half;
            qh[ks] = *(const bf16x8*)&QhiP[qoff + c * 8];
            ql[ks] = *(const bf16x8*)&QloP[qoff + c * 8];
        }
    }

    float mx   = -1e38f;
    float lsum = 0.0f;
    f32x16 oacc[2];
#pragma unroll
    for (int ig = 0; ig < 2; ++ig)
#pragma unroll
        for (int e = 0; e < 16; ++e) oacc[ig][e] = 0.0f;

    const int irow = iw * 32 + l31;

    for (int kt = 0; kt < kSz / 64; ++kt) {
        // ---- QK^T: D = K·Q^T for this wave's (jw, iw) quarter ----
        f32x16 sf;
#pragma unroll
        for (int r = 0; r < 16; ++r) sf[r] = 0.0f;
        {
            const size_t koff = (size_t)(kt * 64 + jw * 32 + l31) * kDH;
#pragma unroll
            for (int ks = 0; ks < 8; ++ks) {
                const int c = 2 * ks + half;
                const bf16x8 kh = *(const bf16x8*)&KhiP[koff + c * 8];
                const bf16x8 kl = *(const bf16x8*)&KloP[koff + c * 8];
                sf = __builtin_amdgcn_mfma_f32_32x32x16_bf16(kh, qh[ks], sf, 0, 0, 0);
                sf = __builtin_amdgcn_mfma_f32_32x32x16_bf16(kh, ql[ks], sf, 0, 0, 0);
                sf = __builtin_amdgcn_mfma_f32_32x32x16_bf16(kl, qh[ks], sf, 0, 0, 0);
            }
        }

        // ---- mask bias (per-lane direct load) + scale + row max ----
        float mb[4][4];
#pragma unroll
        for (int g = 0; g < 4; ++g) {
            const int j0 = kt * 64 + jw * 32 + 8 * g + 4 * half;
            if (mstride == 1) {
                const uchar4 m4 = *(const uchar4*)&mp8[j0];
                mb[g][0] = m4.x ? 0.0f : -1e30f;
                mb[g][1] = m4.y ? 0.0f : -1e30f;
                mb[g][2] = m4.z ? 0.0f : -1e30f;
                mb[g][3] = m4.w ? 0.0f : -1e30f;
            } else {
                const int4 m4 = *(const int4*)&mp32[j0];
                mb[g][0] = m4.x ? 0.0f : -1e30f;
                mb[g][1] = m4.y ? 0.0f : -1e30f;
                mb[g][2] = m4.z ? 0.0f : -1e30f;
                mb[g][3] = m4.w ? 0.0f : -1e30f;
            }
        }
        float sv[16];
        float rmax = -1e38f;
#pragma unroll
        for (int r = 0; r < 16; ++r) {
            const float v = sf[r] * scale + mb[r >> 2][r & 3];
            sv[r] = v;
            rmax  = fmaxf(rmax, v);
        }
        rmax = fmaxf(rmax, __shfl_xor(rmax, 32));
        if (lane < 32) rmaxP[jw][irow] = rmax;
        __syncthreads();  // barrier 1

        // ---- softmax: merge maxima, exp, partial sums, write split P^T ----
        const float mnew  = fmaxf(mx, fmaxf(rmaxP[0][irow], rmaxP[1][irow]));
        const float alpha = __expf(mx - mnew);
        float rs = 0.0f;
#pragma unroll
        for (int r = 0; r < 16; ++r) {
            const float pv = __expf(sv[r] - mnew);
            sv[r] = pv;
            rs += pv;
        }
        rs += __shfl_xor(rs, 32);
        if (lane < 32) rsumP[jw][irow] = rs;
        if (jw == 0 && lane < 32) alphaS[irow] = alpha;
#pragma unroll
        for (int g = 0; g < 4; ++g) {
            ushort4 h4, l4;
            const float v0 = sv[4 * g + 0], v1 = sv[4 * g + 1];
            const float v2 = sv[4 * g + 2], v3 = sv[4 * g + 3];
            h4.x = f2bf_hi(v0); l4.x = f2bf_rne(v0 - bf2f(h4.x));
            h4.y = f2bf_hi(v1); l4.y = f2bf_rne(v1 - bf2f(h4.y));
            h4.z = f2bf_hi(v2); l4.z = f2bf_rne(v2 - bf2f(h4.z));
            h4.w = f2bf_hi(v3); l4.w = f2bf_rne(v3 - bf2f(h4.w));
            const int jo = jw * 32 + 8 * g + 4 * half;
            *(ushort4*)&PtHi[irow * 68 + jo] = h4;
            *(ushort4*)&PtLo[irow * 68 + jo] = l4;
        }
        mx = mnew;
        __syncthreads();  // barrier 2
        lsum = lsum * alpha + (rsumP[0][irow] + rsumP[1][irow]);

        // ---- PV: O^T += Vt · P^T  (wave owns d-slice wid*32..+31) ----
        {
            const float a0 = alphaS[l31];
            const float a1 = alphaS[32 + l31];
#pragma unroll
            for (int e = 0; e < 16; ++e) { oacc[0][e] *= a0; oacc[1][e] *= a1; }

            const size_t voff = (size_t)(wid * 32 + l31) * kSz + kt * 64;
#pragma unroll
            for (int ks = 0; ks < 4; ++ks) {
                const int c = 2 * ks + half;
                const bf16x8 vh = *(const bf16x8*)&VthP[voff + c * 8];
                const bf16x8 vl = *(const bf16x8*)&VtlP[voff + c * 8];
#pragma unroll
                for (int ig = 0; ig < 2; ++ig) {
                    const int ir = ig * 32 + l31;
                    const bf16x8 ph = ld_b64x2(&PtHi[ir * 68 + c * 8]);
                    const bf16x8 pl = ld_b64x2(&PtLo[ir * 68 + c * 8]);
                    oacc[ig] = __builtin_amdgcn_mfma_f32_32x32x16_bf16(vh, ph, oacc[ig], 0, 0, 0);
                    oacc[ig] = __builtin_amdgcn_mfma_f32_32x32x16_bf16(vh, pl, oacc[ig], 0, 0, 0);
                    oacc[ig] = __builtin_amdgcn_mfma_f32_32x32x16_bf16(vl, ph, oacc[ig], 0, 0, 0);
                }
            }
        }
        __syncthreads();  // barrier 3 (Pt/alphaS/partials reusable)
    }

    // ---- normalize, park O split-bf16 in LDS (union over Pt) ----
    if (jw == 0 && lane < 32) linvS[irow] = 1.0f / lsum;
    __syncthreads();
#pragma unroll
    for (int ig = 0; ig < 2; ++ig) {
        const float inv = linvS[ig * 32 + l31];
        const int ir = ig * 32 + l31;
#pragma unroll
        for (int g = 0; g < 4; ++g) {
            ushort4 h4, l4;
            const float v0 = oacc[ig][4 * g + 0] * inv;
            const float v1 = oacc[ig][4 * g + 1] * inv;
            const float v2 = oacc[ig][4 * g + 2] * inv;
            const float v3 = oacc[ig][4 * g + 3] * inv;
            h4.x = f2bf_hi(v0); l4.x = f2bf_rne(v0 - bf2f(h4.x));
            h4.y = f2bf_hi(v1); l4.y = f2bf_rne(v1 - bf2f(h4.y));
            h4.z = f2bf_hi(v2); l4.z = f2bf_rne(v2 - bf2f(h4.z));
            h4.w = f2bf_hi(v3); l4.w = f2bf_rne(v3 - bf2f(h4.w));
            const int dloc = wid * 32 + 8 * g + 4 * half;
            *(ushort4*)&OsHi[ir * 132 + dloc] = h4;
            *(ushort4*)&OsLo[ir * 132 + dloc] = l4;
        }
    }
    __syncthreads();

    // ---- fused out-projection: y^T = Wo · O^T (wave owns e-slice) ----
    f32x16 ya[2];
#pragma unroll
    for (int ig = 0; ig < 2; ++ig)
#pragma unroll
        for (int e = 0; e < 16; ++e) ya[ig][e] = 0.0f;
    {
        const size_t woff = ((size_t)h * kDH + wid * 32 + l31) * kDH;
#pragma unroll
        for (int ks = 0; ks < 8; ++ks) {
            const int c = 2 * ks + half;
            const bf16x8 wh = *(const bf16x8*)&Wohi[woff + c * 8];
            const bf16x8 wl = *(const bf16x8*)&Wolo[woff + c * 8];
#pragma unroll
            for (int ig = 0; ig < 2; ++ig) {
                const int ir = ig * 32 + l31;
                const bf16x8 oh = ld_b64x2(&OsHi[ir * 132 + c * 8]);
                const bf16x8 ol = ld_b64x2(&OsLo[ir * 132 + c * 8]);
                ya[ig] = __builtin_amdgcn_mfma_f32_32x32x16_bf16(wh, oh, ya[ig], 0, 0, 0);
                ya[ig] = __builtin_amdgcn_mfma_f32_32x32x16_bf16(wh, ol, ya[ig], 0, 0, 0);
                ya[ig] = __builtin_amdgcn_mfma_f32_32x32x16_bf16(wl, oh, ya[ig], 0, 0, 0);
            }
        }
    }
#pragma unroll
    for (int ig = 0; ig < 2; ++ig) {
        const int i = s0 + ig * 32 + l31;
        float* orow = out + ((size_t)(bb * kSz + i)) * kDz + h * kDH;
#pragma unroll
        for (int g = 0; g < 4; ++g) {
            const int e0 = wid * 32 + 8 * g + 4 * half;
            const float4 bo4 = *(const float4*)&bo[h * kDH + e0];
            float4 y;
            y.x = ya[ig][4 * g + 0] + bo4.x;
            y.y = ya[ig][4 * g + 1] + bo4.y;
            y.z = ya[ig][4 * g + 2] + bo4.z;
            y.w = ya[ig][4 * g + 3] + bo4.w;
            *(float4*)&orow[e0] = y;
        }
    }
}

// ---------------------------------------------------------------------------
extern "C" void kernel_launch(void* const* d_in, const int* in_sizes, int n_in,
                              void* d_out, int out_size, void* d_ws, size_t ws_size,
                              hipStream_t stream)
{
    (void)in_sizes; (void)n_in; (void)out_size; (void)ws_size;
    const float*   x    = (const float*)d_in[0];
    const uint8_t* mask = (const uint8_t*)d_in[1];
    const float*   Wq   = (const float*)d_in[2];
    const float*   bq   = (const float*)d_in[3];
    const float*   Wk   = (const float*)d_in[4];
    const float*   bk   = (const float*)d_in[5];
    const float*   Wv   = (const float*)d_in[6];
    const float*   bv   = (const float*)d_in[7];
    const float*   Wo   = (const float*)d_in[8];
    const float*   bo   = (const float*)d_in[9];
    float* out = (float*)d_out;

    // workspace: Qhi,Qlo,Khi,Klo (B,H,S,DH) + Vthi,Vtlo (B,H,DH,S) bf16
    // planes (6 x 16.78 MB) + Wohi,Wolo (2 x 0.5 MB) = 101.7 MB.
    const size_t plane = (size_t)kBz * kHz * kSz * kDH;  // 8,388,608 elems
    ushort* Qhi  = (ushort*)d_ws;
    ushort* Qlo  = Qhi + plane;
    ushort* Khi  = Qlo + plane;
    ushort* Klo  = Khi + plane;
    ushort* Vthi = Klo + plane;
    ushort* Vtlo = Vthi + plane;
    ushort* Wohi = Vtlo + plane;
    ushort* Wolo = Wohi + (size_t)kHz * kDH * kDH;

    wo_split_kernel<<<dim3(kHz * kDH * kDH / 1024), 256, 0, stream>>>(Wo, Wohi, Wolo);
    qkv_proj_kernel<<<dim3(kDz / 128, kMz / 128, 3), 256, 0, stream>>>(
        x, Wq, Wk, Wv, bq, bk, bv, Qhi, Qlo, Khi, Klo, Vthi, Vtlo);
    attn_fused_kernel<<<dim3((kSz / 64) * kBz * kHz), 256, 0, stream>>>(
        Qhi, Qlo, Khi, Klo, Vthi, Vtlo, mask, Wohi, Wolo, bo, out);
}